// Round 1
// 683.944 us; speedup vs baseline: 1.1057x; 1.1057x over previous
//
#include <hip/hip_runtime.h>
#include <hip/hip_bf16.h>

// GCN_5016521802361: 2x SAGEConv(aggr='lstm', project=True), N=50000, D=16, F=128, C=40.
// Round 14: lstm_aggr restructure.
//  (1) Wave-private stage slices: each wave DMAs only the 128B/row slice it reads
//      (per-lane swizzled global src, linear LDS dest). Stage has NO cross-wave
//      dependency -> per-step sync is lgkmcnt(0)+s_barrier only (no vmcnt drain).
//  (2) 2-deep gather pipeline with counted s_waitcnt vmcnt(2) at point-of-use
//      (vmcnt(0) only at t=15). DMA latency leaves the barrier critical path.
//  (3) exp2-prescale: Wih/Whh/bih/bhh scaled by log2e (g-gate rows by 2*log2e) in
//      convert_inputs; cell uses native v_exp_f32 with free neg modifiers, c kept
//      in 2*log2e units, merged single-rcp c-path: 8->7 trans, -5 muls per cell.
//  (4) t=0 MFMA skipped (h0=0), hb zero-init dropped.

typedef __hip_bfloat16 bf16;
typedef __attribute__((ext_vector_type(8))) short short8;
typedef __attribute__((ext_vector_type(4))) short short4v;
typedef __attribute__((ext_vector_type(4))) float floatx4;

#define LOG2E 1.4426950408889634f
#define TWOL  2.8853900817779268f

__device__ __forceinline__ float bf2f(bf16 v) { return __bfloat162float(v); }
__device__ __forceinline__ bf16  f2bf(float v) { return __float2bfloat16(v); }
__device__ __forceinline__ float bfs2f(short s) {
    union { float f; unsigned u; } v; v.u = ((unsigned)(unsigned short)s) << 16; return v.f;
}
__device__ __forceinline__ short f2bfs(float v) {
    bf16 b = __float2bfloat16(v); return *(short*)&b;
}

__device__ __forceinline__ float ex2(float x) {
#if __has_builtin(__builtin_amdgcn_exp2f)
    return __builtin_amdgcn_exp2f(x);
#else
    return exp2f(x);
#endif
}

// LSTM cell, prescaled inputs: i_,f_,o_ carry log2e, g_ carries 2*log2e,
// c is tracked as (2*log2e)*c_true. Single merged rcp on the c path.
__device__ __forceinline__ float cell(float i_, float f_, float g_, float o_, float& c) {
    float ei = ex2(-i_), ef = ex2(-f_), eg = ex2(g_), eo = ex2(-o_);
    float A = (1.f + ei) * (eg + 1.f);
    float B = 1.f + ef;
    // c'' = [c''*A + 2L*(eg-1)*B] / (A*B)
    float cn = fmaf(c, A, fmaf(eg, TWOL, -TWOL) * B) * __builtin_amdgcn_rcpf(A * B);
    c = cn;
    float ec = ex2(cn);
    return (ec - 1.f) * __builtin_amdgcn_rcpf((ec + 1.f) * (1.f + eo));
}

// Permuted-Y memory position p <-> gate column: p = w*64 + q*16 + g*4 + r where
// the gate col cg = g*128 + (16w + 4q + r). Writers decode p -> source row.
__device__ __forceinline__ int ydecode(int p) {
    int pw = (p >> 6) & 7, pq = (p >> 4) & 3, pg = (p >> 2) & 3, pr = p & 3;
    return pg * 128 + pw * 16 + pq * 4 + pr;
}

// two 16B/lane global->LDS DMAs covering a wave's 2KB slice (gp per-lane is legal;
// LDS dest must be wave-uniform base + lane*16)
__device__ __forceinline__ void dma2(const bf16* gp, void* lp0, void* lp1) {
    __builtin_amdgcn_global_load_lds(
        (const __attribute__((address_space(1))) void*)gp,
        (__attribute__((address_space(3))) void*)lp0, 16, 0, 0);
    __builtin_amdgcn_global_load_lds(
        (const __attribute__((address_space(1))) void*)(gp + 32),
        (__attribute__((address_space(3))) void*)lp1, 16, 0, 0);
}

__global__ void detect_dtype(const unsigned short* __restrict__ xb, int* __restrict__ flag) {
    int cnt = 0;
    for (int i = threadIdx.x; i < 1024; i += 64) {
        int e = (xb[i] >> 7) & 0xFF;
        cnt += (e >= 0xC8);
    }
#pragma unroll
    for (int off = 32; off; off >>= 1) cnt += __shfl_down(cnt, off);
    if (threadIdx.x == 0) *flag = (cnt >= 16) ? 1 : 0;   // 1 => inputs are float32
}

struct Cvt { const void* src; bf16* dst; int n; int gs; };
struct CvtAll { Cvt t[19]; };

__global__ void convert_inputs(CvtAll ca, const int* __restrict__ flag) {
    const bool isf32 = (*flag != 0);
    const int stride = gridDim.x * blockDim.x;
    const int tid0 = blockIdx.x * blockDim.x + threadIdx.x;
#pragma unroll 1
    for (int k = 0; k < 19; k++) {
        const int n = ca.t[k].n, gs = ca.t[k].gs;
        const float* sf = (const float*)ca.t[k].src;
        const bf16*  sb = (const bf16*)ca.t[k].src;
        bf16* d = ca.t[k].dst;
        for (int i = tid0; i < n; i += stride) {
            float v = isf32 ? sf[i] : bf2f(sb[i]);
            if (gs) v *= ((((unsigned)i >> gs) & 3) == 2) ? TWOL : LOG2E;
            d[i] = f2bf(v);
        }
    }
}

// generic (final lin2 layer)
template <int NCT, bool RELU, bool BIAS2, bool DUAL, bool OUTF>
__global__ __launch_bounds__(256, 2) void gemm_bias(
    const bf16* __restrict__ A, const bf16* __restrict__ B,
    const bf16* __restrict__ bias, const bf16* __restrict__ bias2,
    const bf16* __restrict__ A2, const bf16* __restrict__ B2,
    void* __restrict__ Cv, const int* __restrict__ oflag,
    int N, int nbt, int ldc)
{
    const int tid = threadIdx.x;
    const int w = tid >> 6, l = tid & 63, q = l >> 4, lid = l & 15;
    const int rowbase = blockIdx.x * 64 + w * 16;
    const int colslice = blockIdx.y * (NCT * 16);

    int arow = rowbase + lid;
    if (arow >= N) arow = N - 1;

    floatx4 acc[NCT];
#pragma unroll
    for (int ct = 0; ct < NCT; ct++) acc[ct] = (floatx4)(0.f);

    short8 bfrag[NCT][4];
#pragma unroll
    for (int ct = 0; ct < NCT; ct++) {
        int j = colslice + ct * 16 + lid;
        if (j >= nbt) j = nbt - 1;
#pragma unroll
        for (int kt = 0; kt < 4; kt++)
            bfrag[ct][kt] = *(const short8*)(B + (size_t)j * 128 + kt * 32 + q * 8);
    }
#pragma unroll
    for (int kt = 0; kt < 4; kt++) {
        short8 af = *(const short8*)(A + (size_t)arow * 128 + kt * 32 + q * 8);
#pragma unroll
        for (int ct = 0; ct < NCT; ct++)
            acc[ct] = __builtin_amdgcn_mfma_f32_16x16x32_bf16(af, bfrag[ct][kt], acc[ct], 0, 0, 0);
    }
    if constexpr (DUAL) {
#pragma unroll
        for (int ct = 0; ct < NCT; ct++) {
            int j = colslice + ct * 16 + lid;
            if (j >= nbt) j = nbt - 1;
#pragma unroll
            for (int kt = 0; kt < 4; kt++)
                bfrag[ct][kt] = *(const short8*)(B2 + (size_t)j * 128 + kt * 32 + q * 8);
        }
#pragma unroll
        for (int kt = 0; kt < 4; kt++) {
            short8 af = *(const short8*)(A2 + (size_t)arow * 128 + kt * 32 + q * 8);
#pragma unroll
            for (int ct = 0; ct < NCT; ct++)
                acc[ct] = __builtin_amdgcn_mfma_f32_16x16x32_bf16(af, bfrag[ct][kt], acc[ct], 0, 0, 0);
        }
    }
    bool of32 = false;
    if constexpr (OUTF) of32 = (*oflag != 0);
#pragma unroll
    for (int ct = 0; ct < NCT; ct++) {
        int cg = colslice + ct * 16 + lid;
        int cb = cg < nbt ? cg : nbt - 1;
        float bv = bf2f(bias[cb]);
        if constexpr (BIAS2) bv += bf2f(bias2[cb]);
#pragma unroll
        for (int r = 0; r < 4; r++) {
            int row = rowbase + q * 4 + r;
            float v = acc[ct][r] + bv;
            if constexpr (RELU) v = fmaxf(v, 0.f);
            if (row < N && cg < nbt) {
                size_t idx = (size_t)row * ldc + cg;
                if constexpr (OUTF) {
                    if (of32) ((float*)Cv)[idx] = v;
                    else      ((bf16*)Cv)[idx] = f2bf(v);
                } else {
                    ((bf16*)Cv)[idx] = f2bf(v);
                }
            }
        }
    }
}

// ---------------------------------------------------------------------------
// Fused layer entry: Y = (relu(X@Wp^T+bp)) @ Wih^T + bih + bhh, permuted layout
// via SOURCE-ROW indexing (Wih/bih/bhh arrive prescaled by log2e / 2*log2e).
// ---------------------------------------------------------------------------
__global__ __launch_bounds__(256, 2) void fused_xp_y(
    const bf16* __restrict__ X, const bf16* __restrict__ Wp, const bf16* __restrict__ bp,
    const bf16* __restrict__ Wih, const bf16* __restrict__ bih, const bf16* __restrict__ bhh,
    bf16* __restrict__ Yout, int N)
{
    __shared__ bf16 T[64][136];
    const int tid = threadIdx.x;
    const int w = tid >> 6, l = tid & 63, q = l >> 4, lid = l & 15;
    const int rowbase = blockIdx.x * 64;

    int arow = rowbase + w * 16 + lid;
    if (arow >= N) arow = N - 1;

    floatx4 acc[8];
    short8 bfrag[8][4];

    // ---- stage A: xp = relu(X@Wp^T + bp) -> T ----
#pragma unroll
    for (int ct = 0; ct < 8; ct++) acc[ct] = (floatx4)(0.f);
#pragma unroll
    for (int ct = 0; ct < 8; ct++) {
        int j = ct * 16 + lid;
#pragma unroll
        for (int kt = 0; kt < 4; kt++)
            bfrag[ct][kt] = *(const short8*)(Wp + (size_t)j * 128 + kt * 32 + q * 8);
    }
#pragma unroll
    for (int kt = 0; kt < 4; kt++) {
        short8 af = *(const short8*)(X + (size_t)arow * 128 + kt * 32 + q * 8);
#pragma unroll
        for (int ct = 0; ct < 8; ct++)
            acc[ct] = __builtin_amdgcn_mfma_f32_16x16x32_bf16(af, bfrag[ct][kt], acc[ct], 0, 0, 0);
    }
#pragma unroll
    for (int ct = 0; ct < 8; ct++) {
        int col = ct * 16 + lid;
        float bv = bf2f(bp[col]);
#pragma unroll
        for (int r = 0; r < 4; r++)
            T[w * 16 + q * 4 + r][col] = f2bf(fmaxf(acc[ct][r] + bv, 0.f));
    }
    __syncthreads();

    // ---- stage B: Y chunks, contiguous stores, permute via source-row index ----
#pragma unroll 1
    for (int cc = 0; cc < 4; cc++) {
#pragma unroll
        for (int ct = 0; ct < 8; ct++) {
            int jm = cc * 128 + ct * 16 + lid;      // memory column
            int src = ydecode(jm);                  // source gate row
#pragma unroll
            for (int kt = 0; kt < 4; kt++)
                bfrag[ct][kt] = *(const short8*)(Wih + (size_t)src * 128 + kt * 32 + q * 8);
        }
#pragma unroll
        for (int ct = 0; ct < 8; ct++) acc[ct] = (floatx4)(0.f);
#pragma unroll
        for (int kt = 0; kt < 4; kt++) {
            short8 af = *(const short8*)&T[w * 16 + lid][kt * 32 + q * 8];
#pragma unroll
            for (int ct = 0; ct < 8; ct++)
                acc[ct] = __builtin_amdgcn_mfma_f32_16x16x32_bf16(af, bfrag[ct][kt], acc[ct], 0, 0, 0);
        }
#pragma unroll
        for (int ct = 0; ct < 8; ct++) {
            int jm = cc * 128 + ct * 16 + lid;
            int src = ydecode(jm);
            float bv = bf2f(bih[src]) + bf2f(bhh[src]);
#pragma unroll
            for (int r = 0; r < 4; r++) {
                int row = rowbase + w * 16 + q * 4 + r;
                if (row < N) Yout[(size_t)row * 512 + jm] = f2bf(acc[ct][r] + bv);
            }
        }
    }
}

// ---------------------------------------------------------------------------
// Fused between-layers: h1 = relu(aggr@Wl^T+bl+X@Wr^T) (global+LDS);
// xp2 = relu(h1@Wp2^T+bp2) (LDS); Y2 = permuted via source-row indexing.
// ---------------------------------------------------------------------------
__global__ __launch_bounds__(256, 2) void fused_lin_xp_y(
    const bf16* __restrict__ aggr, const bf16* __restrict__ Wl, const bf16* __restrict__ bl,
    const bf16* __restrict__ X, const bf16* __restrict__ Wr,
    bf16* __restrict__ h1out,
    const bf16* __restrict__ Wp2, const bf16* __restrict__ bp2,
    const bf16* __restrict__ Wih2, const bf16* __restrict__ bih2, const bf16* __restrict__ bhh2,
    bf16* __restrict__ Yout, int N)
{
    __shared__ bf16 T1[64][136];
    __shared__ bf16 T2[64][136];
    const int tid = threadIdx.x;
    const int w = tid >> 6, l = tid & 63, q = l >> 4, lid = l & 15;
    const int rowbase = blockIdx.x * 64;

    int arow = rowbase + w * 16 + lid;
    if (arow >= N) arow = N - 1;

    floatx4 acc[8];
    short8 bfrag[8][4];

    // ---- stage A: h1 ----
#pragma unroll
    for (int ct = 0; ct < 8; ct++) acc[ct] = (floatx4)(0.f);
#pragma unroll
    for (int ct = 0; ct < 8; ct++) {
        int j = ct * 16 + lid;
#pragma unroll
        for (int kt = 0; kt < 4; kt++)
            bfrag[ct][kt] = *(const short8*)(Wl + (size_t)j * 128 + kt * 32 + q * 8);
    }
#pragma unroll
    for (int kt = 0; kt < 4; kt++) {
        short8 af = *(const short8*)(aggr + (size_t)arow * 128 + kt * 32 + q * 8);
#pragma unroll
        for (int ct = 0; ct < 8; ct++)
            acc[ct] = __builtin_amdgcn_mfma_f32_16x16x32_bf16(af, bfrag[ct][kt], acc[ct], 0, 0, 0);
    }
#pragma unroll
    for (int ct = 0; ct < 8; ct++) {
        int j = ct * 16 + lid;
#pragma unroll
        for (int kt = 0; kt < 4; kt++)
            bfrag[ct][kt] = *(const short8*)(Wr + (size_t)j * 128 + kt * 32 + q * 8);
    }
#pragma unroll
    for (int kt = 0; kt < 4; kt++) {
        short8 af = *(const short8*)(X + (size_t)arow * 128 + kt * 32 + q * 8);
#pragma unroll
        for (int ct = 0; ct < 8; ct++)
            acc[ct] = __builtin_amdgcn_mfma_f32_16x16x32_bf16(af, bfrag[ct][kt], acc[ct], 0, 0, 0);
    }
#pragma unroll
    for (int ct = 0; ct < 8; ct++) {
        int col = ct * 16 + lid;
        float bv = bf2f(bl[col]);
#pragma unroll
        for (int r = 0; r < 4; r++) {
            int rl = w * 16 + q * 4 + r;
            bf16 hv = f2bf(fmaxf(acc[ct][r] + bv, 0.f));
            T1[rl][col] = hv;
            int row = rowbase + rl;
            if (row < N) h1out[(size_t)row * 128 + col] = hv;
        }
    }
    __syncthreads();

    // ---- stage B: xp2 -> T2 ----
#pragma unroll
    for (int ct = 0; ct < 8; ct++) {
        int j = ct * 16 + lid;
#pragma unroll
        for (int kt = 0; kt < 4; kt++)
            bfrag[ct][kt] = *(const short8*)(Wp2 + (size_t)j * 128 + kt * 32 + q * 8);
    }
#pragma unroll
    for (int ct = 0; ct < 8; ct++) acc[ct] = (floatx4)(0.f);
#pragma unroll
    for (int kt = 0; kt < 4; kt++) {
        short8 af = *(const short8*)&T1[w * 16 + lid][kt * 32 + q * 8];
#pragma unroll
        for (int ct = 0; ct < 8; ct++)
            acc[ct] = __builtin_amdgcn_mfma_f32_16x16x32_bf16(af, bfrag[ct][kt], acc[ct], 0, 0, 0);
    }
#pragma unroll
    for (int ct = 0; ct < 8; ct++) {
        int col = ct * 16 + lid;
        float bv = bf2f(bp2[col]);
#pragma unroll
        for (int r = 0; r < 4; r++)
            T2[w * 16 + q * 4 + r][col] = f2bf(fmaxf(acc[ct][r] + bv, 0.f));
    }
    __syncthreads();

    // ---- stage C: Y2 chunks, contiguous stores, permute via source-row index ----
#pragma unroll 1
    for (int cc = 0; cc < 4; cc++) {
#pragma unroll
        for (int ct = 0; ct < 8; ct++) {
            int jm = cc * 128 + ct * 16 + lid;
            int src = ydecode(jm);
#pragma unroll
            for (int kt = 0; kt < 4; kt++)
                bfrag[ct][kt] = *(const short8*)(Wih2 + (size_t)src * 128 + kt * 32 + q * 8);
        }
#pragma unroll
        for (int ct = 0; ct < 8; ct++) acc[ct] = (floatx4)(0.f);
#pragma unroll
        for (int kt = 0; kt < 4; kt++) {
            short8 af = *(const short8*)&T2[w * 16 + lid][kt * 32 + q * 8];
#pragma unroll
            for (int ct = 0; ct < 8; ct++)
                acc[ct] = __builtin_amdgcn_mfma_f32_16x16x32_bf16(af, bfrag[ct][kt], acc[ct], 0, 0, 0);
        }
#pragma unroll
        for (int ct = 0; ct < 8; ct++) {
            int jm = cc * 128 + ct * 16 + lid;
            int src = ydecode(jm);
            float bv = bf2f(bih2[src]) + bf2f(bhh2[src]);
#pragma unroll
            for (int r = 0; r < 4; r++) {
                int row = rowbase + w * 16 + q * 4 + r;
                if (row < N) Yout[(size_t)row * 512 + jm] = f2bf(acc[ct][r] + bv);
            }
        }
    }
}

// ---------------------------------------------------------------------------
// LSTM neighbor aggregation, round-14 structure.
// 512 thr / 8 waves / 16 nodes. Wave w owns hidden cols [16w,16w+16).
// Stage is WAVE-PRIVATE: wave w stages, for every node-row, only the 128B slice
// of the permuted Y row it consumes. LDS chunk (row,c) lives at byte c*256+row*16
// (linear DMA dest); global src is per-lane swizzled. Reads are 8-phase
// conflict-free. Gather runs 2 steps deep with counted vmcnt(2); the per-step
// barrier carries only lgkmcnt(0) (hb exchange) — no vmcnt drain.
// ---------------------------------------------------------------------------
__global__ __launch_bounds__(512, 4) void lstm_aggr(
    const bf16* __restrict__ Y,     // [N,512] PERMUTED, prescaled pre-activations
    const int* __restrict__ esrc,   // [N,16]
    const bf16* __restrict__ Whh,   // [512,128] prescaled by gate
    bf16* __restrict__ aggr,        // [N,128] out: final h
    int N)
{
    __shared__ alignas(16) short stage[2][8][1024];  // [buf][wave][2KB slice]
    __shared__ alignas(16) bf16 hb[2][16][136];
    __shared__ int srcl[16][16];    // [t][node]

    const int tid = threadIdx.x;
    const int w = tid >> 6, l = tid & 63, q = l >> 4, lid = l & 15;
    const int nodebase = blockIdx.x * 16;   // N = 50000 = 3125*16, exact

    if (tid < 256) {
        int node = tid >> 4, t = tid & 15;
        srcl[t][node] = esrc[(size_t)(nodebase + node) * 16 + t];
    }

    // Whh A-fragments: wf[g][kt]; A-row = gatecol = g*128 + 16*w + lid
    short8 wf[4][4];
#pragma unroll
    for (int g = 0; g < 4; g++) {
        int gc = g * 128 + 16 * w + lid;
#pragma unroll
        for (int kt = 0; kt < 4; kt++)
            wf[g][kt] = *(const short8*)(Whh + (size_t)gc * 128 + kt * 32 + q * 8);
    }

    float c[4];
#pragma unroll
    for (int r = 0; r < 4; r++) c[r] = 0.f;

    // DMA source swizzle: lane l of issue0 fills LDS chunk (row=l&15, c=l>>4)
    // = global bytes [w*128 + (l>>4)*16) of Y row srcl[t][l&15]; issue1 = +64B.
    const int laneoff = w * 64 + q * 8;   // bf16 elements within a Y row

    __syncthreads();   // srcl visible before first DMA

    // prologue: prefetch t=0 and t=1 slices (oldest-first: pair0 then pair1)
    {
        int s0 = srcl[0][lid];
        dma2(Y + (size_t)s0 * 512 + laneoff, &stage[0][w][0], &stage[0][w][512]);
        int s1 = srcl[1][lid];
        dma2(Y + (size_t)s1 * 512 + laneoff, &stage[1][w][0], &stage[1][w][512]);
    }

#pragma unroll 2
    for (int t = 0; t < 16; t++) {
        const int cb = t & 1;

        // own slice for step t landed; keep the t+1 pair in flight
        if (t == 15) asm volatile("s_waitcnt vmcnt(0)" ::: "memory");
        else         asm volatile("s_waitcnt vmcnt(2)" ::: "memory");

        int snext = (t < 14) ? srcl[t + 2][lid] : 0;

        floatx4 acc[4];
        {
            const short* wbuf = &stage[cb][w][0];
            short8 y0 = *(const short8*)&wbuf[q * 256 + lid * 8];
            short8 y1 = *(const short8*)&wbuf[q * 256 + 128 + lid * 8];
#pragma unroll
            for (int g = 0; g < 2; g++)
#pragma unroll
                for (int r = 0; r < 4; r++) {
                    acc[g][r]     = bfs2f(y0[g * 4 + r]);
                    acc[2 + g][r] = bfs2f(y1[g * 4 + r]);
                }
        }

        if (t) {   // h0 = 0: skip recurrent MFMA at t=0 (hb never read uninit)
#pragma unroll
            for (int kt = 0; kt < 4; kt++) {
                short8 bh = *(const short8*)&hb[cb][lid][kt * 32 + q * 8];
#pragma unroll
                for (int g = 0; g < 4; g++)
                    acc[g] = __builtin_amdgcn_mfma_f32_16x16x32_bf16(wf[g][kt], bh, acc[g], 0, 0, 0);
            }
        }

        {
            short4v hv;
#pragma unroll
            for (int r = 0; r < 4; r++)
                hv[r] = f2bfs(cell(acc[0][r], acc[1][r], acc[2][r], acc[3][r], c[r]));
            if (t < 15) *(short4v*)&hb[cb ^ 1][lid][16 * w + 4 * q] = hv;
            else        *(short4v*)(aggr + (size_t)(nodebase + lid) * 128 + 16 * w + 4 * q) = hv;
        }

        if (t < 15) {
            // my stage[cb] reads + hb write retired; stage[cb] is free to refill
            asm volatile("s_waitcnt lgkmcnt(0)" ::: "memory");
            if (t < 14)
                dma2(Y + (size_t)snext * 512 + laneoff, &stage[cb][w][0], &stage[cb][w][512]);
            __builtin_amdgcn_s_barrier();   // hb exchange only — no vmcnt drain
        }
    }
}

extern "C" void kernel_launch(void* const* d_in, const int* in_sizes, int n_in,
                              void* d_out, int out_size, void* d_ws, size_t ws_size,
                              hipStream_t stream)
{
    const int N = 50000;
    const int* es = (const int*)d_in[1];
    char* ws = (char*)d_ws;

    // converted bf16 copies of the 19 used float tensors @[0,15MB)
    static const int idxs[19] = {0, 8,9,10,11,12,13,14,15,16, 17,18,19,20,21,22,23,24,25};
    // exp2-prescale: Wih/Whh -> gate = (i>>14)&3 ; bih/bhh -> gate = (i>>7)&3
    static const int gss[19]  = {0, 0,0,14,14,7,7,0,0,0, 0,0,14,14,7,7,0,0,0};
    bf16* conv[19];
    size_t off = 0;
    CvtAll ca;
    for (int k = 0; k < 19; k++) {
        conv[k] = (bf16*)ws + off;
        ca.t[k].src = d_in[idxs[k]];
        ca.t[k].dst = conv[k];
        ca.t[k].n = in_sizes[idxs[k]];
        ca.t[k].gs = gss[k];
        off += (size_t)((in_sizes[idxs[k]] + 63) & ~63);
    }
    int* flag = (int*)(ws + ((size_t)15 << 20));
    bf16* aggr = (bf16*)(ws + ((size_t)16 << 20));   // [N,128]
    bf16* Y    = (bf16*)(ws + ((size_t)30 << 20));   // [N,512] permuted
    bf16* h1   = (bf16*)(ws + ((size_t)84 << 20));   // [N,128]

    const bf16 *xc  = conv[0];
    const bf16 *Wp1 = conv[1],  *bp1 = conv[2],  *Wih1 = conv[3],  *Whh1 = conv[4];
    const bf16 *bih1 = conv[5], *bhh1 = conv[6], *Wl1 = conv[7],   *bl1 = conv[8],  *Wr1 = conv[9];
    const bf16 *Wp2 = conv[10], *bp2 = conv[11], *Wih2 = conv[12], *Whh2 = conv[13];
    const bf16 *bih2 = conv[14], *bhh2 = conv[15], *Wl2 = conv[16], *bl2 = conv[17], *Wr2 = conv[18];

    dim3 blk(256);
    const int gx = (N + 63) / 64;    // 782
    const int gl = N / 16;           // 3125 (exact)

    detect_dtype<<<dim3(1), dim3(64), 0, stream>>>((const unsigned short*)d_in[0], flag);
    convert_inputs<<<dim3(1024), blk, 0, stream>>>(ca, flag);

    // ---- layer 1 ----
    fused_xp_y<<<dim3(gx), blk, 0, stream>>>(xc, Wp1, bp1, Wih1, bih1, bhh1, Y, N);
    lstm_aggr<<<dim3(gl), dim3(512), 0, stream>>>(Y, es, Whh1, aggr, N);

    // ---- between layers: lin1 -> xp2 -> Y2 ----
    fused_lin_xp_y<<<dim3(gx), blk, 0, stream>>>(
        aggr, Wl1, bl1, xc, Wr1, h1, Wp2, bp2, Wih2, bih2, bhh2, Y, N);
    lstm_aggr<<<dim3(gl), dim3(512), 0, stream>>>(Y, es, Whh2, aggr, N);

    // ---- final: out = lin_l2(aggr) + bl2 + lin_r2(h1) ----
    gemm_bias<3, false, false, true, true><<<dim3(gx, 1), blk, 0, stream>>>(
        aggr, Wl2, bl2, nullptr, h1, Wr2, d_out, flag, N, 40, 40);
}